// Round 5
// baseline (227.100 us; speedup 1.0000x reference)
//
#include <hip/hip_runtime.h>
#include <hip/hip_bf16.h>

#define BB 8
#define NN 16384
#define D1 256
#define D2 64
#define DT 320
#define EPSF 1e-12f
#define NCG 32          // K chunks
#define KCH 512         // rows per chunk
#define QSZ (160*320)   // partial slice elems

typedef __attribute__((ext_vector_type(8))) short bf16x8;
typedef __attribute__((ext_vector_type(8))) unsigned short u16x8;
typedef __attribute__((ext_vector_type(4))) float f32x4;
typedef __attribute__((ext_vector_type(4))) unsigned int u32x4;

__device__ __forceinline__ unsigned int packbf2(float a, float b) {
    unsigned short lo = __builtin_bit_cast(unsigned short, __float2bfloat16(a));
    unsigned short hi = __builtin_bit_cast(unsigned short, __float2bfloat16(b));
    return (unsigned int)lo | ((unsigned int)hi << 16);
}
__device__ __forceinline__ float bf2f(unsigned short u) {
    unsigned int x = (unsigned int)u << 16;
    return __builtin_bit_cast(float, x);
}

// 8-unit swizzle over the [c][64-row] tile (row stride 128B -> all banks reachable):
// element (c, n8*8+k) -> unit u = (n8 ^ sig(c)) & 7. Verified conflict-clean for
// b128 staging writes (c = 4*lane+cidx) and <=2-way for frag reads (c = 16m+l15).
__device__ __forceinline__ int sig(int c) { return (c ^ (c >> 2)) & 7; }

// ---------------- kernel 1: s[b,c] = sum_n Y[b,n,c] ----------------
__global__ void colsum_kernel(const float* __restrict__ Y, float* __restrict__ s) {
    const int b = blockIdx.y;
    const int chunk = blockIdx.x;          // 0..31, 512 rows each
    const int t = threadIdx.x;             // 256
    const int c = t & 63;
    const int r = t >> 6;                  // 0..3
    const float* Yb = Y + (size_t)b * NN * D2;
    float acc = 0.f;
    const int nbase = chunk * 512;
    for (int k = 0; k < 128; ++k) {
        int n = nbase + k * 4 + r;
        acc += Yb[(size_t)n * D2 + c];
    }
    __shared__ float red[256];
    red[t] = acc;
    __syncthreads();
    if (r == 0) {
        float v = red[c] + red[64 + c] + red[128 + c] + red[192 + c];
        atomicAdd(&s[b * D2 + c], v);
    }
}

// ---------------- kernel 2: rsd[b,n] = (Y[b,n,:].s[b,:] + eps)^(-1/4) ----------------
__global__ void rsd_kernel(const float* __restrict__ Y, const float* __restrict__ s,
                           float* __restrict__ rsd) {
    const int blk = blockIdx.x;            // 2048 blocks
    const int b = blk >> 8;
    const int nb = (blk & 255) * 64;
    const int t = threadIdx.x;             // 256
    const int q = t & 3;
    const int nl = t >> 2;
    __shared__ float ss[D2];
    if (t < D2) ss[t] = s[b * D2 + t];
    __syncthreads();
    const int n = nb + nl;
    const float* yrow = Y + (size_t)b * NN * D2 + (size_t)n * D2 + q * 16;
    float dot = 0.f;
#pragma unroll
    for (int i = 0; i < 4; ++i) {
        float4 f = *reinterpret_cast<const float4*>(yrow + i * 4);
        const float* sp = ss + q * 16 + i * 4;
        dot += f.x * sp[0] + f.y * sp[1] + f.z * sp[2] + f.w * sp[3];
    }
    dot += __shfl_xor(dot, 1);
    dot += __shfl_xor(dot, 2);
    if (q == 0) {
        rsd[(size_t)b * NN + n] = rsqrtf(sqrtf(dot + EPSF));
    }
}

// ---------------- kernel 3 helpers ----------------
__device__ __forceinline__ void issue_loads(const float* __restrict__ Vb,
                                            const float* __restrict__ Yb,
                                            const float* __restrict__ rb,
                                            int n0w, int lane,
                                            float4* vf, float4* yf, float* rr) {
#pragma unroll
    for (int j = 0; j < 8; ++j)
        vf[j] = *reinterpret_cast<const float4*>(Vb + (size_t)(n0w + j) * D1 + 4 * lane);
    const int j2 = lane >> 4, k15 = lane & 15;
    yf[0] = *reinterpret_cast<const float4*>(Yb + (size_t)(n0w + 2 * j2) * D2 + 4 * k15);
    yf[1] = *reinterpret_cast<const float4*>(Yb + (size_t)(n0w + 2 * j2 + 1) * D2 + 4 * k15);
#pragma unroll
    for (int j = 0; j < 8; ++j) rr[j] = rb[n0w + j];
}

__device__ __forceinline__ void write_tile(unsigned short* __restrict__ x,
                                           int lane, int w,
                                           const float4* vf, const float4* yf,
                                           const float* rr) {
    const float* vfp = reinterpret_cast<const float*>(vf);
    const float* yfp = reinterpret_cast<const float*>(yf);
    // V columns: c = 4*lane + cidx; 8 rows (this wave's) -> one b128 at unit (w^sig(c))&7
#pragma unroll
    for (int cidx = 0; cidx < 4; ++cidx) {
        const int c = 4 * lane + cidx;
        const int u = (w ^ sig(c)) & 7;
        u32x4 p;
        p[0] = packbf2(vfp[0 * 4 + cidx] * rr[0], vfp[1 * 4 + cidx] * rr[1]);
        p[1] = packbf2(vfp[2 * 4 + cidx] * rr[2], vfp[3 * 4 + cidx] * rr[3]);
        p[2] = packbf2(vfp[4 * 4 + cidx] * rr[4], vfp[5 * 4 + cidx] * rr[5]);
        p[3] = packbf2(vfp[6 * 4 + cidx] * rr[6], vfp[7 * 4 + cidx] * rr[7]);
        *reinterpret_cast<u32x4*>(&x[c * 64 + u * 8]) = p;
    }
    // Y columns: c = D1 + 4*k15 + cidx; rows (2*j2, 2*j2+1) -> u32 slot j2
    const int j2 = lane >> 4, k15 = lane & 15;
    const float r0 = rr[2 * j2], r1 = rr[2 * j2 + 1];
#pragma unroll
    for (int cidx = 0; cidx < 4; ++cidx) {
        const int c = D1 + 4 * k15 + cidx;
        const int u = (w ^ sig(c)) & 7;
        unsigned int p = packbf2(yfp[0 * 4 + cidx] * r0, yfp[1 * 4 + cidx] * r1);
        *reinterpret_cast<unsigned int*>(&x[c * 64 + u * 8 + j2 * 2]) = p;
    }
}

// ---------------- kernel 3: band Gram over a 512-row chunk ----------------
// grid (32 cg, 2 bands, 8 b) = 512 blocks = 2/CU; 512 thr (8 waves: 2x4 of 80x80)
__global__ void __launch_bounds__(512, 4)
gram_kernel(const float* __restrict__ V, const float* __restrict__ Y,
            const float* __restrict__ rsd, unsigned short* __restrict__ Gpart,
            float* __restrict__ Gfull, int priv) {
    const int cg = blockIdx.x;     // 0..31
    const int band = blockIdx.y;   // 0..1
    const int b = blockIdx.z;
    const int t = threadIdx.x;
    const int lane = t & 63;
    const int w = t >> 6;
    const int wrow = w >> 2;       // 0..1
    const int wcol = w & 3;        // 0..3
    const int l15 = lane & 15;
    const int l4 = lane >> 4;

    const float* Vb = V + (size_t)b * NN * D1;
    const float* Yb = Y + (size_t)b * NN * D2;
    const float* rb = rsd + (size_t)b * NN;

    __shared__ __attribute__((aligned(16))) unsigned short xt[2][DT * 64];  // 80 KB

    f32x4 acc[5][5];
#pragma unroll
    for (int i = 0; i < 5; ++i)
#pragma unroll
        for (int j = 0; j < 5; ++j)
            acc[i][j] = (f32x4){0.f, 0.f, 0.f, 0.f};

    float4 vf[8];
    float4 yf[2];
    float rr[8];

    const int n0base = cg * KCH;

    issue_loads(Vb, Yb, rb, n0base + 8 * w, lane, vf, yf, rr);
    write_tile(xt[0], lane, w, vf, yf, rr);
    __syncthreads();

    for (int tt = 0; tt < 8; ++tt) {       // 8 tiles of 64 rows = 512
        if (tt < 7)
            issue_loads(Vb, Yb, rb, n0base + (tt + 1) * 64 + 8 * w, lane, vf, yf, rr);

        const unsigned short* x = xt[tt & 1];
#pragma unroll
        for (int ks = 0; ks < 2; ++ks) {
            const int n8r = 2 * l4 + ks;   // K-block remap, A/B consistent
            bf16x8 af[5], bfr[5];
#pragma unroll
            for (int i = 0; i < 5; ++i) {
                const int ca = band * 160 + wrow * 80 + i * 16 + l15;
                af[i] = *reinterpret_cast<const bf16x8*>(
                    &x[ca * 64 + ((n8r ^ sig(ca)) & 7) * 8]);
                const int cb = wcol * 80 + i * 16 + l15;
                bfr[i] = *reinterpret_cast<const bf16x8*>(
                    &x[cb * 64 + ((n8r ^ sig(cb)) & 7) * 8]);
            }
#pragma unroll
            for (int i = 0; i < 5; ++i)
#pragma unroll
                for (int j = 0; j < 5; ++j)
                    acc[i][j] = __builtin_amdgcn_mfma_f32_16x16x32_bf16(
                        af[i], bfr[j], acc[i][j], 0, 0, 0);
        }

        if (tt < 7)
            write_tile(xt[(tt + 1) & 1], lane, w, vf, yf, rr);
        __syncthreads();
    }

    if (priv) {
        // bf16 partial: slice = (b*2+band)*32 + cg, layout [160][320]
        unsigned short* Gp = Gpart + (size_t)((b * 2 + band) * NCG + cg) * QSZ;
#pragma unroll
        for (int i = 0; i < 5; ++i) {
            const int gi_base = wrow * 80 + i * 16 + l4 * 4;
#pragma unroll
            for (int j = 0; j < 5; ++j) {
                const int gj = wcol * 80 + j * 16 + l15;
#pragma unroll
                for (int rg = 0; rg < 4; ++rg)
                    Gp[(size_t)(gi_base + rg) * DT + gj] = __builtin_bit_cast(
                        unsigned short, __float2bfloat16(acc[i][j][rg]));
            }
        }
    } else {
        float* Gb = Gfull + (size_t)b * DT * DT;
#pragma unroll
        for (int i = 0; i < 5; ++i) {
            const int gi_base = band * 160 + wrow * 80 + i * 16 + l4 * 4;
#pragma unroll
            for (int j = 0; j < 5; ++j) {
                const int gj = wcol * 80 + j * 16 + l15;
#pragma unroll
                for (int rg = 0; rg < 4; ++rg)
                    atomicAdd(&Gb[(size_t)(gi_base + rg) * DT + gj], acc[i][j][rg]);
            }
        }
    }
}

// ---------------- kernel 4a: reduce 32 bf16 partials -> weighted square sum ------
// grid (25, 16): y = b*2+band, x = slice of 2048 elems (8 per thread)
__global__ void loss_priv_kernel(const unsigned short* __restrict__ Gpart,
                                 float* __restrict__ out) {
    const int by = blockIdx.y;             // b*2 + band
    const int band = by & 1;
    const int t = threadIdx.x;             // 256
    const int e0 = (blockIdx.x * 256 + t) * 8;   // into 51200, 16B-aligned
    float g[8];
#pragma unroll
    for (int k = 0; k < 8; ++k) g[k] = 0.f;
    const unsigned short* base = Gpart + (size_t)by * NCG * QSZ + e0;
#pragma unroll 4
    for (int cg = 0; cg < NCG; ++cg) {
        u16x8 p = *reinterpret_cast<const u16x8*>(base + (size_t)cg * QSZ);
#pragma unroll
        for (int k = 0; k < 8; ++k) g[k] += bf2f(p[k]);
    }
    const int ii = e0 / DT;
    const int jj = e0 - ii * DT;           // multiple of 8; all 8 same side of 256
    const int ig = band * 160 + ii;
    const float wgt = ((ig < D1) == (jj < D1)) ? 1.f : -1.f;
    float sum = 0.f;
#pragma unroll
    for (int k = 0; k < 8; ++k) sum += g[k] * g[k];
    sum *= wgt;
#pragma unroll
    for (int off = 1; off < 64; off <<= 1) sum += __shfl_xor(sum, off);
    __shared__ float red[4];
    if ((t & 63) == 0) red[t >> 6] = sum;
    __syncthreads();
    if (t == 0) atomicAdd(out, (red[0] + red[1] + red[2] + red[3]) * 0.125f);
}

// ---------------- kernel 4b: fallback loss over accumulated full G ----------------
__global__ void loss_kernel(const float* __restrict__ G, float* __restrict__ out) {
    const int b = blockIdx.x >> 3;
    const int slice = blockIdx.x & 7;
    const int t = threadIdx.x;
    const float* Gb = G + (size_t)b * DT * DT;
    float sum = 0.f;
    for (int k = 0; k < 50; ++k) {
        const int e = slice * 12800 + k * 256 + t;
        const int i = e / DT;
        const int j = e - i * DT;
        const float gv = Gb[e];
        const float w = ((i < D1) == (j < D1)) ? 1.f : -1.f;
        sum += w * gv * gv;
    }
#pragma unroll
    for (int off = 1; off < 64; off <<= 1) sum += __shfl_xor(sum, off);
    __shared__ float red[4];
    if ((t & 63) == 0) red[t >> 6] = sum;
    __syncthreads();
    if (t == 0) atomicAdd(out, (red[0] + red[1] + red[2] + red[3]) * 0.125f);
}

extern "C" void kernel_launch(void* const* d_in, const int* in_sizes, int n_in,
                              void* d_out, int out_size, void* d_ws, size_t ws_size,
                              hipStream_t stream) {
    const float* V = (const float*)d_in[0];
    const float* Y = (const float*)d_in[1];
    float* out = (float*)d_out;

    char* ws = (char*)d_ws;
    float* s    = (float*)ws;                              // 2048 B
    float* rsd  = (float*)(ws + 2048);                     // 524288 B
    unsigned short* Gpart = (unsigned short*)(ws + 2048 + 524288);  // 52.43 MB bf16
    float* Gfull = (float*)(ws + 2048 + 524288);           // fallback 3.28 MB fp32

    const size_t need_priv = 2048 + 524288 + (size_t)BB * 2 * NCG * QSZ * 2;
    const int priv = (ws_size >= need_priv) ? 1 : 0;

    hipMemsetAsync(s, 0, 2048, stream);
    if (!priv) hipMemsetAsync(Gfull, 0, (size_t)BB * DT * DT * 4, stream);
    hipMemsetAsync(d_out, 0, sizeof(float), stream);

    colsum_kernel<<<dim3(32, BB), 256, 0, stream>>>(Y, s);
    rsd_kernel<<<2048, 256, 0, stream>>>(Y, s, rsd);
    gram_kernel<<<dim3(NCG, 2, BB), 512, 0, stream>>>(V, Y, rsd, Gpart, Gfull, priv);
    if (priv)
        loss_priv_kernel<<<dim3(25, 16), 256, 0, stream>>>(Gpart, out);
    else
        loss_kernel<<<64, 256, 0, stream>>>(Gfull, out);
}

// Round 6
// 86.890 us; speedup vs baseline: 2.6136x; 2.6136x over previous
//
#include <hip/hip_runtime.h>
#include <hip/hip_bf16.h>

#define BB 8
#define NN 16384
#define D1 256
#define D2 64
#define DT 320
#define EPSF 1e-12f
#define NCG 32          // K chunks
#define KCH 512         // rows per chunk
#define QSZ (160*320)   // partial slice elems

typedef __attribute__((ext_vector_type(8))) short bf16x8;
typedef __attribute__((ext_vector_type(8))) unsigned short u16x8;
typedef __attribute__((ext_vector_type(4))) float f32x4;
typedef __attribute__((ext_vector_type(4))) unsigned int u32x4;

__device__ __forceinline__ unsigned int packbf2(float a, float b) {
    unsigned short lo = __builtin_bit_cast(unsigned short, __float2bfloat16(a));
    unsigned short hi = __builtin_bit_cast(unsigned short, __float2bfloat16(b));
    return (unsigned int)lo | ((unsigned int)hi << 16);
}
__device__ __forceinline__ float bf2f(unsigned short u) {
    unsigned int x = (unsigned int)u << 16;
    return __builtin_bit_cast(float, x);
}

// 8-unit swizzle over the [c][64-row] tile (row stride 128B):
// element (c, n8*8+k) -> unit u = (n8 ^ sig(c)) & 7. Conflict-clean for b128
// staging writes (c = 4*lane+cidx) and <=2-way for frag reads (c = 16m+l15).
__device__ __forceinline__ int sig(int c) { return (c ^ (c >> 2)) & 7; }

// ---------------- kernel 1: s[b,c] = sum_n Y[b,n,c] ----------------
__global__ void colsum_kernel(const float* __restrict__ Y, float* __restrict__ s) {
    const int b = blockIdx.y;
    const int chunk = blockIdx.x;          // 0..31, 512 rows each
    const int t = threadIdx.x;             // 256
    const int c = t & 63;
    const int r = t >> 6;                  // 0..3
    const float* Yb = Y + (size_t)b * NN * D2;
    float acc = 0.f;
    const int nbase = chunk * 512;
    for (int k = 0; k < 128; ++k) {
        int n = nbase + k * 4 + r;
        acc += Yb[(size_t)n * D2 + c];
    }
    __shared__ float red[256];
    red[t] = acc;
    __syncthreads();
    if (r == 0) {
        float v = red[c] + red[64 + c] + red[128 + c] + red[192 + c];
        atomicAdd(&s[b * D2 + c], v);
    }
}

// ---------------- kernel 2: rsd[b,n] = (Y[b,n,:].s[b,:] + eps)^(-1/4) ----------------
__global__ void rsd_kernel(const float* __restrict__ Y, const float* __restrict__ s,
                           float* __restrict__ rsd) {
    const int blk = blockIdx.x;            // 2048 blocks
    const int b = blk >> 8;
    const int nb = (blk & 255) * 64;
    const int t = threadIdx.x;             // 256
    const int q = t & 3;
    const int nl = t >> 2;
    __shared__ float ss[D2];
    if (t < D2) ss[t] = s[b * D2 + t];
    __syncthreads();
    const int n = nb + nl;
    const float* yrow = Y + (size_t)b * NN * D2 + (size_t)n * D2 + q * 16;
    float dot = 0.f;
#pragma unroll
    for (int i = 0; i < 4; ++i) {
        float4 f = *reinterpret_cast<const float4*>(yrow + i * 4);
        const float* sp = ss + q * 16 + i * 4;
        dot += f.x * sp[0] + f.y * sp[1] + f.z * sp[2] + f.w * sp[3];
    }
    dot += __shfl_xor(dot, 1);
    dot += __shfl_xor(dot, 2);
    if (q == 0) {
        rsd[(size_t)b * NN + n] = rsqrtf(sqrtf(dot + EPSF));
    }
}

// ---------------- kernel 3 helpers ----------------
__device__ __forceinline__ void issue_loads(const float* __restrict__ Vb,
                                            const float* __restrict__ Yb,
                                            const float* __restrict__ rb,
                                            int n0w, int lane,
                                            float4* vf, float4* yf, float* rr) {
#pragma unroll
    for (int j = 0; j < 8; ++j)
        vf[j] = *reinterpret_cast<const float4*>(Vb + (size_t)(n0w + j) * D1 + 4 * lane);
    const int j2 = lane >> 4, k15 = lane & 15;
    yf[0] = *reinterpret_cast<const float4*>(Yb + (size_t)(n0w + 2 * j2) * D2 + 4 * k15);
    yf[1] = *reinterpret_cast<const float4*>(Yb + (size_t)(n0w + 2 * j2 + 1) * D2 + 4 * k15);
#pragma unroll
    for (int j = 0; j < 8; ++j) rr[j] = rb[n0w + j];
}

__device__ __forceinline__ void write_tile(unsigned short* __restrict__ x,
                                           int lane, int w,
                                           const float4* vf, const float4* yf,
                                           const float* rr) {
    const float* vfp = reinterpret_cast<const float*>(vf);
    const float* yfp = reinterpret_cast<const float*>(yf);
    // V columns: c = 4*lane + cidx; 8 rows (this wave's) -> one b128 at unit (w^sig(c))&7
#pragma unroll
    for (int cidx = 0; cidx < 4; ++cidx) {
        const int c = 4 * lane + cidx;
        const int u = (w ^ sig(c)) & 7;
        u32x4 p;
        p[0] = packbf2(vfp[0 * 4 + cidx] * rr[0], vfp[1 * 4 + cidx] * rr[1]);
        p[1] = packbf2(vfp[2 * 4 + cidx] * rr[2], vfp[3 * 4 + cidx] * rr[3]);
        p[2] = packbf2(vfp[4 * 4 + cidx] * rr[4], vfp[5 * 4 + cidx] * rr[5]);
        p[3] = packbf2(vfp[6 * 4 + cidx] * rr[6], vfp[7 * 4 + cidx] * rr[7]);
        *reinterpret_cast<u32x4*>(&x[c * 64 + u * 8]) = p;
    }
    // Y columns: c = D1 + 4*k15 + cidx; rows (2*j2, 2*j2+1) -> u32 slot j2
    const int j2 = lane >> 4, k15 = lane & 15;
    const float r0 = rr[2 * j2], r1 = rr[2 * j2 + 1];
#pragma unroll
    for (int cidx = 0; cidx < 4; ++cidx) {
        const int c = D1 + 4 * k15 + cidx;
        const int u = (w ^ sig(c)) & 7;
        unsigned int p = packbf2(yfp[0 * 4 + cidx] * r0, yfp[1 * 4 + cidx] * r1);
        *reinterpret_cast<unsigned int*>(&x[c * 64 + u * 8 + j2 * 2]) = p;
    }
}

// ---------------- kernel 3: band Gram over a 512-row chunk ----------------
// grid (32 cg, 2 bands, 8 b) = 512 blocks = 2/CU; 512 thr (8 waves: 2x4 of 80x80)
// Single-buffered 40 KB LDS so 2 blocks fit per CU; cross-block overlap hides
// the per-phase latency (this is the whole point of this round).
__global__ void __launch_bounds__(512, 2)
gram_kernel(const float* __restrict__ V, const float* __restrict__ Y,
            const float* __restrict__ rsd, unsigned short* __restrict__ Gpart,
            float* __restrict__ Gfull, int priv) {
    const int cg = blockIdx.x;     // 0..31
    const int band = blockIdx.y;   // 0..1
    const int b = blockIdx.z;
    const int t = threadIdx.x;
    const int lane = t & 63;
    const int w = t >> 6;
    const int wrow = w >> 2;       // 0..1
    const int wcol = w & 3;        // 0..3
    const int l15 = lane & 15;
    const int l4 = lane >> 4;

    const float* Vb = V + (size_t)b * NN * D1;
    const float* Yb = Y + (size_t)b * NN * D2;
    const float* rb = rsd + (size_t)b * NN;

    __shared__ __attribute__((aligned(16))) unsigned short xt[DT * 64];  // 40 KB

    f32x4 acc[5][5];
#pragma unroll
    for (int i = 0; i < 5; ++i)
#pragma unroll
        for (int j = 0; j < 5; ++j)
            acc[i][j] = (f32x4){0.f, 0.f, 0.f, 0.f};

    float4 vf[8];
    float4 yf[2];
    float rr[8];

    const int n0base = cg * KCH;

    // prologue: stage tile 0
    issue_loads(Vb, Yb, rb, n0base + 8 * w, lane, vf, yf, rr);
    write_tile(xt, lane, w, vf, yf, rr);

    for (int tt = 0; tt < 8; ++tt) {       // 8 tiles of 64 rows = 512
        __syncthreads();                   // staged writes visible

        if (tt < 7)                        // prefetch next tile into registers
            issue_loads(Vb, Yb, rb, n0base + (tt + 1) * 64 + 8 * w, lane, vf, yf, rr);

#pragma unroll
        for (int ks = 0; ks < 2; ++ks) {
            const int n8r = 2 * l4 + ks;   // K-block remap, A/B consistent
            bf16x8 af[5], bfr[5];
#pragma unroll
            for (int i = 0; i < 5; ++i) {
                const int ca = band * 160 + wrow * 80 + i * 16 + l15;
                af[i] = *reinterpret_cast<const bf16x8*>(
                    &xt[ca * 64 + ((n8r ^ sig(ca)) & 7) * 8]);
                const int cb = wcol * 80 + i * 16 + l15;
                bfr[i] = *reinterpret_cast<const bf16x8*>(
                    &xt[cb * 64 + ((n8r ^ sig(cb)) & 7) * 8]);
            }
#pragma unroll
            for (int i = 0; i < 5; ++i)
#pragma unroll
                for (int j = 0; j < 5; ++j)
                    acc[i][j] = __builtin_amdgcn_mfma_f32_16x16x32_bf16(
                        af[i], bfr[j], acc[i][j], 0, 0, 0);
        }

        __syncthreads();                   // all frag reads done
        if (tt < 7)
            write_tile(xt, lane, w, vf, yf, rr);
    }

    if (priv) {
        // bf16 partial: slice = (b*2+band)*32 + cg, layout [160][320]
        unsigned short* Gp = Gpart + (size_t)((b * 2 + band) * NCG + cg) * QSZ;
#pragma unroll
        for (int i = 0; i < 5; ++i) {
            const int gi_base = wrow * 80 + i * 16 + l4 * 4;
#pragma unroll
            for (int j = 0; j < 5; ++j) {
                const int gj = wcol * 80 + j * 16 + l15;
#pragma unroll
                for (int rg = 0; rg < 4; ++rg)
                    Gp[(size_t)(gi_base + rg) * DT + gj] = __builtin_bit_cast(
                        unsigned short, __float2bfloat16(acc[i][j][rg]));
            }
        }
    } else {
        float* Gb = Gfull + (size_t)b * DT * DT;
#pragma unroll
        for (int i = 0; i < 5; ++i) {
            const int gi_base = band * 160 + wrow * 80 + i * 16 + l4 * 4;
#pragma unroll
            for (int j = 0; j < 5; ++j) {
                const int gj = wcol * 80 + j * 16 + l15;
#pragma unroll
                for (int rg = 0; rg < 4; ++rg)
                    atomicAdd(&Gb[(size_t)(gi_base + rg) * DT + gj], acc[i][j][rg]);
            }
        }
    }
}

// ---------------- kernel 4a: reduce 32 bf16 partials -> weighted square sum ------
// grid (25, 16): y = b*2+band, x = slice of 2048 elems (8 per thread)
__global__ void loss_priv_kernel(const unsigned short* __restrict__ Gpart,
                                 float* __restrict__ out) {
    const int by = blockIdx.y;             // b*2 + band
    const int band = by & 1;
    const int t = threadIdx.x;             // 256
    const int e0 = (blockIdx.x * 256 + t) * 8;   // into 51200, 16B-aligned
    float g[8];
#pragma unroll
    for (int k = 0; k < 8; ++k) g[k] = 0.f;
    const unsigned short* base = Gpart + (size_t)by * NCG * QSZ + e0;
#pragma unroll 4
    for (int cg = 0; cg < NCG; ++cg) {
        u16x8 p = *reinterpret_cast<const u16x8*>(base + (size_t)cg * QSZ);
#pragma unroll
        for (int k = 0; k < 8; ++k) g[k] += bf2f(p[k]);
    }
    const int ii = e0 / DT;
    const int jj = e0 - ii * DT;           // multiple of 8; all 8 same side of 256
    const int ig = band * 160 + ii;
    const float wgt = ((ig < D1) == (jj < D1)) ? 1.f : -1.f;
    float sum = 0.f;
#pragma unroll
    for (int k = 0; k < 8; ++k) sum += g[k] * g[k];
    sum *= wgt;
#pragma unroll
    for (int off = 1; off < 64; off <<= 1) sum += __shfl_xor(sum, off);
    __shared__ float red[4];
    if ((t & 63) == 0) red[t >> 6] = sum;
    __syncthreads();
    if (t == 0) atomicAdd(out, (red[0] + red[1] + red[2] + red[3]) * 0.125f);
}

// ---------------- kernel 4b: fallback loss over accumulated full G ----------------
__global__ void loss_kernel(const float* __restrict__ G, float* __restrict__ out) {
    const int b = blockIdx.x >> 3;
    const int slice = blockIdx.x & 7;
    const int t = threadIdx.x;
    const float* Gb = G + (size_t)b * DT * DT;
    float sum = 0.f;
    for (int k = 0; k < 50; ++k) {
        const int e = slice * 12800 + k * 256 + t;
        const int i = e / DT;
        const int j = e - i * DT;
        const float gv = Gb[e];
        const float w = ((i < D1) == (j < D1)) ? 1.f : -1.f;
        sum += w * gv * gv;
    }
#pragma unroll
    for (int off = 1; off < 64; off <<= 1) sum += __shfl_xor(sum, off);
    __shared__ float red[4];
    if ((t & 63) == 0) red[t >> 6] = sum;
    __syncthreads();
    if (t == 0) atomicAdd(out, (red[0] + red[1] + red[2] + red[3]) * 0.125f);
}

extern "C" void kernel_launch(void* const* d_in, const int* in_sizes, int n_in,
                              void* d_out, int out_size, void* d_ws, size_t ws_size,
                              hipStream_t stream) {
    const float* V = (const float*)d_in[0];
    const float* Y = (const float*)d_in[1];
    float* out = (float*)d_out;

    char* ws = (char*)d_ws;
    float* s    = (float*)ws;                              // 2048 B
    float* rsd  = (float*)(ws + 2048);                     // 524288 B
    unsigned short* Gpart = (unsigned short*)(ws + 2048 + 524288);  // 52.43 MB bf16
    float* Gfull = (float*)(ws + 2048 + 524288);           // fallback 3.28 MB fp32

    const size_t need_priv = 2048 + 524288 + (size_t)BB * 2 * NCG * QSZ * 2;
    const int priv = (ws_size >= need_priv) ? 1 : 0;

    hipMemsetAsync(s, 0, 2048, stream);
    if (!priv) hipMemsetAsync(Gfull, 0, (size_t)BB * DT * DT * 4, stream);
    hipMemsetAsync(d_out, 0, sizeof(float), stream);

    colsum_kernel<<<dim3(32, BB), 256, 0, stream>>>(Y, s);
    rsd_kernel<<<2048, 256, 0, stream>>>(Y, s, rsd);
    gram_kernel<<<dim3(NCG, 2, BB), 512, 0, stream>>>(V, Y, rsd, Gpart, Gfull, priv);
    if (priv)
        loss_priv_kernel<<<dim3(25, 16), 256, 0, stream>>>(Gpart, out);
    else
        loss_kernel<<<64, 256, 0, stream>>>(Gfull, out);
}